// Round 6
// baseline (3193.349 us; speedup 1.0000x reference)
//
#include <hip/hip_runtime.h>
#include <cstdint>
#include <cstddef>

// ---------------------------------------------------------------------------
// Problem constants
// ---------------------------------------------------------------------------
constexpr int NB = 256;   // batch
constexpr int NC = 512;   // c_length
constexpr int NL = 16;    // lattice side
constexpr int NFS = 15;   // neighborhood size

#define PARTITIONABLE 1

// ---------------------------------------------------------------------------
// Threefry2x32-20 (JAX-compatible), usable at compile time and on device
// ---------------------------------------------------------------------------
struct TFOut { uint32_t a, b; };

__host__ __device__ constexpr uint32_t rotl32(uint32_t x, int d) {
  return (x << d) | (x >> (32 - d));
}

__host__ __device__ constexpr TFOut tf2x32(uint32_t k0, uint32_t k1,
                                           uint32_t x0, uint32_t x1) {
  uint32_t k2 = k0 ^ k1 ^ 0x1BD11BDAu;
  x0 += k0; x1 += k1;
  const int R0[4] = {13, 15, 26, 6};
  const int R1[4] = {17, 29, 16, 24};
  for (int i = 0; i < 4; i++) { x0 += x1; x1 = rotl32(x1, R0[i]); x1 ^= x0; }
  x0 += k1; x1 += k2 + 1u;
  for (int i = 0; i < 4; i++) { x0 += x1; x1 = rotl32(x1, R1[i]); x1 ^= x0; }
  x0 += k2; x1 += k0 + 2u;
  for (int i = 0; i < 4; i++) { x0 += x1; x1 = rotl32(x1, R0[i]); x1 ^= x0; }
  x0 += k0; x1 += k1 + 3u;
  for (int i = 0; i < 4; i++) { x0 += x1; x1 = rotl32(x1, R1[i]); x1 ^= x0; }
  x0 += k1; x1 += k2 + 4u;
  for (int i = 0; i < 4; i++) { x0 += x1; x1 = rotl32(x1, R0[i]); x1 ^= x0; }
  x0 += k2; x1 += k0 + 5u;
  return TFOut{x0, x1};
}

struct SubKeys { uint32_t v[288]; };

constexpr SubKeys make_subkeys() {
  SubKeys s{};
  uint32_t k0 = 0u, k1 = 1234u;
  for (int t = 0; t < 144; t++) {
#if PARTITIONABLE
    TFOut nk = tf2x32(k0, k1, 0u, 0u);
    TFOut sk = tf2x32(k0, k1, 0u, 1u);
    s.v[2 * t] = sk.a; s.v[2 * t + 1] = sk.b;
    k0 = nk.a; k1 = nk.b;
#else
    TFOut p0 = tf2x32(k0, k1, 0u, 2u);
    TFOut p1 = tf2x32(k0, k1, 1u, 3u);
    s.v[2 * t] = p0.b; s.v[2 * t + 1] = p1.b;
    k0 = p0.a; k1 = p1.a;
#endif
  }
  return s;
}

__constant__ SubKeys SUBKEYS = make_subkeys();

__device__ __forceinline__ float gumbel_from_bits(uint32_t bits) {
  uint32_t ub = (bits >> 9) | 0x3f800000u;
  float f = __uint_as_float(ub) - 1.0f;
  float u = (f == 0.0f) ? 1.17549435e-38f : f;
  float inner = logf(u);
  float outer = logf(-inner);
  return -outer;
}

// ---------------------------------------------------------------------------
// Kernel 0: init workspace + outputs
// ---------------------------------------------------------------------------
__global__ __launch_bounds__(256) void setup_kernel(
    const float* __restrict__ u_in, const int* __restrict__ v_in,
    float* __restrict__ h0buf, float* __restrict__ cbuf,
    float* __restrict__ u_cur, int* __restrict__ v_cur,
    float* __restrict__ out_soft, float* __restrict__ out_u,
    float* __restrict__ out_v) {
  int idx = blockIdx.x * 256 + threadIdx.x;
  h0buf[idx] = 0.0f;                         // 2 parities x [4][NB][NC]
  if (idx < 3 * NB * NC) cbuf[idx] = 0.0f;   // lstm cell state, 3 sectors
  if (idx < NB * NL * NL) {
    float uv = u_in[idx];
    int vv = v_in[idx];
    u_cur[idx] = uv;
    v_cur[idx] = vv;
    out_u[idx] = uv;
    out_v[idx] = (float)vv;
  }
  if (idx < NB * NL * NL * 2) out_soft[idx] = 0.0f;
}

// ---------------------------------------------------------------------------
// Kernel 1: WD[n][c] = W1 · (emb[n,1]-emb[n,0]);  A0 = W1 · Σ emb[n,0] + b1
// ---------------------------------------------------------------------------
__global__ __launch_bounds__(256) void wd_kernel(
    const float* __restrict__ emb, const float* __restrict__ w1,
    const float* __restrict__ b1, float* __restrict__ WD,
    float* __restrict__ A0v) {
  __shared__ double dvec[NC];
  int n = blockIdx.x, tid = threadIdx.x;
  for (int k = tid; k < NC; k += 256) {
    if (n < NFS) {
      dvec[k] = (double)emb[(n * 2 + 1) * NC + k] - (double)emb[(n * 2) * NC + k];
    } else {
      double s = 0.0;
      for (int nn = 0; nn < NFS; nn++) s += (double)emb[(nn * 2) * NC + k];
      dvec[k] = s;
    }
  }
  __syncthreads();
  for (int c = tid; c < NC; c += 256) {
    double acc = 0.0;
    const float* wrow = w1 + (size_t)c * NC;
    for (int k = 0; k < NC; k++) acc += dvec[k] * (double)wrow[k];
    if (n < NFS) WD[n * NC + c] = (float)acc;
    else         A0v[c] = (float)(acc + (double)b1[c]);
  }
}

// ---------------------------------------------------------------------------
// Kernel 2a: LSTM GEMM, split-K=2, 8x8 per-thread tile (0.5 LDS-B/FLOP).
// Block = 64 rows x 64 cols, 64 threads (one wave), grid = 12*32*2 = 768.
// LDS rows stride 32 words with XOR swizzle physk4 = kk4 ^ (row>>3) so both
// the staging writes and the 8-way-broadcast reads hit the minimal
// 8 word-accesses/bank (padded strides would alias one bank).
// kz=0: k in [0,256); kz=1: k in [256,512) + 16-k uv@wih^T term.
// Per-output k-order identical to round 5 -> bit-identical results.
// ---------------------------------------------------------------------------
__global__ __launch_bounds__(64) void lstm_gemm_kernel(
    const float* __restrict__ u_cur, const float* __restrict__ whh,
    const float* __restrict__ wih, const float* __restrict__ h_in,
    float* __restrict__ gpart, int col0) {
  int bx = blockIdx.x;
  int kz = bx & 1;
  int t = bx >> 1;                 // [0,384)
  int ct = t & 31;                 // 32 col tiles of 64
  int rt = t >> 5;                 // 12 row tiles of 64
  int row0 = rt * 64;              // global row in [0,768)
  int colbase = ct * 64;           // global col in [0,2048)
  int tid = threadIdx.x;
  int tcol = tid & 7, trow = tid >> 3;

  __shared__ float hs[64 * 32];
  __shared__ float wt[64 * 32];
  __shared__ float uvs[64 * 17];

  if (kz == 1) {
    int s = row0 >> 8;
    int b0 = row0 & 255;
#pragma unroll
    for (int q = 0; q < 16; q++) {
      int lin = q * 64 + tid;
      int row = lin >> 4, n = lin & 15;
      uvs[row * 17 + n] =
          u_cur[(b0 + row) * 256 + (s * 4 + (n >> 2)) * 16 + col0 + (n & 3)];
    }
  }

  float acc[8][8] = {};
  const float* hbase = h_in + (size_t)row0 * NC;
  int kbase = kz * 256;

  for (int kc = 0; kc < 8; kc++) {
    int k0 = kbase + kc * 32;
    __syncthreads();
#pragma unroll
    for (int q = 0; q < 8; q++) {
      int lin = q * 64 + tid;            // [0,512)
      int r = lin >> 3, kk4 = lin & 7;
      int pk = (kk4 ^ (r >> 3)) * 4;
      *(float4*)&hs[r * 32 + pk] =
          *(const float4*)(hbase + (size_t)r * NC + k0 + kk4 * 4);
      *(float4*)&wt[r * 32 + pk] =
          *(const float4*)(whh + (size_t)(colbase + r) * NC + k0 + kk4 * 4);
    }
    __syncthreads();
#pragma unroll
    for (int kk4 = 0; kk4 < 8; kk4++) {
      float4 hv[8], wv[8];
      int hoff = (kk4 ^ trow) * 4;
      int woff = (kk4 ^ tcol) * 4;
#pragma unroll
      for (int i = 0; i < 8; i++)
        hv[i] = *(float4*)&hs[(trow * 8 + i) * 32 + hoff];
#pragma unroll
      for (int j = 0; j < 8; j++)
        wv[j] = *(float4*)&wt[(tcol * 8 + j) * 32 + woff];
#pragma unroll
      for (int i = 0; i < 8; i++)
#pragma unroll
        for (int j = 0; j < 8; j++)
          acc[i][j] += hv[i].x * wv[j].x + hv[i].y * wv[j].y +
                       hv[i].z * wv[j].z + hv[i].w * wv[j].w;
    }
  }

  float* gp = gpart + (size_t)kz * 768 * 2048;
#pragma unroll
  for (int i = 0; i < 8; i++) {
    int grow = row0 + trow * 8 + i;
    if (kz == 1) {
#pragma unroll
      for (int j = 0; j < 8; j++) {
        int col = colbase + tcol * 8 + j;
        const float* wrow = wih + (size_t)col * 16;
        float extra = 0.0f;
#pragma unroll
        for (int nn = 0; nn < 16; nn++)
          extra += uvs[(trow * 8 + i) * 17 + nn] * wrow[nn];
        acc[i][j] += extra;
      }
    }
    float4 v0 = make_float4(acc[i][0], acc[i][1], acc[i][2], acc[i][3]);
    float4 v1 = make_float4(acc[i][4], acc[i][5], acc[i][6], acc[i][7]);
    *(float4*)&gp[(size_t)grow * 2048 + colbase + tcol * 8] = v0;
    *(float4*)&gp[(size_t)grow * 2048 + colbase + tcol * 8 + 4] = v1;
  }
}

// ---------------------------------------------------------------------------
// Kernel 2b: reduce split-K partials + bias + LSTM nonlinearity.
// 768 rows x 512 cols; grid = 1536 x 256.
// ---------------------------------------------------------------------------
__global__ __launch_bounds__(256) void lstm_gates_kernel(
    const float* __restrict__ gpart, const float* __restrict__ bih,
    const float* __restrict__ bhh, float* __restrict__ h_out,
    float* __restrict__ cbuf) {
  int idx = blockIdx.x * 256 + threadIdx.x;   // [0, 393216)
  int row = idx >> 9, c = idx & 511;
  const float* gp0 = gpart;
  const float* gp1 = gpart + (size_t)768 * 2048;
  size_t base = (size_t)row * 2048 + c;
  float gv[4];
#pragma unroll
  for (int g = 0; g < 4; g++) {
    int nidx = g * 512 + c;
    gv[g] = gp0[base + g * 512] + gp1[base + g * 512] + bih[nidx] + bhh[nidx];
  }
  size_t off = (size_t)row * NC + c;
  float c_old = cbuf[off];
  float sig_i = 1.0f / (1.0f + expf(-gv[0]));
  float sig_f = 1.0f / (1.0f + expf(-gv[1]));
  float tg    = tanhf(gv[2]);
  float sig_o = 1.0f / (1.0f + expf(-gv[3]));
  float cn = sig_f * c_old + sig_i * tg;
  float hn = sig_o * tanhf(cn);
  cbuf[off] = cn;
  h_out[off] = hn;
}

// ---------------------------------------------------------------------------
// Kernel 3: Hpart[ks][b][c] partials of H = W1 · h0 (round-2 LDS version)
// grid = 8(ks,K=64 each) * 4(bt) * 8(ct) = 256 blocks, 256 threads.
// ---------------------------------------------------------------------------
__global__ __launch_bounds__(256) void w1h0_kernel(
    const float* __restrict__ h_in,   // [NB][NC] slice for (parity, s=i)
    const float* __restrict__ w1, float* __restrict__ Hpart) {
  int bx = blockIdx.x;
  int ks = bx >> 5;
  int bt = (bx >> 3) & 3;
  int ct = bx & 7;
  int tid = threadIdx.x, tn = tid & 15, tb = tid >> 4;

  __shared__ float hs[64][36];
  __shared__ float wt[64][36];
  float acc[4][4] = {};
  const float* hbase = h_in + (size_t)(bt * 64) * NC;

  for (int kc = 0; kc < 2; kc++) {
    int k0 = ks * 64 + kc * 32;
    __syncthreads();
    for (int t = 0; t < 2; t++) {
      int idx = tid + t * 256;
      int row = idx >> 3, kk4 = idx & 7;
      *(float4*)&hs[row][kk4 * 4] =
          *(const float4*)(hbase + (size_t)row * NC + k0 + kk4 * 4);
      int wrow = ct * 64 + row;
      *(float4*)&wt[row][kk4 * 4] =
          *(const float4*)(w1 + (size_t)wrow * NC + k0 + kk4 * 4);
    }
    __syncthreads();
#pragma unroll
    for (int kk4 = 0; kk4 < 8; kk4++) {
      float4 hv[4], wv[4];
#pragma unroll
      for (int i = 0; i < 4; i++) hv[i] = *(float4*)&hs[tb * 4 + i][kk4 * 4];
#pragma unroll
      for (int j = 0; j < 4; j++) wv[j] = *(float4*)&wt[tn + 16 * j][kk4 * 4];
#pragma unroll
      for (int i = 0; i < 4; i++)
#pragma unroll
        for (int j = 0; j < 4; j++)
          acc[i][j] += hv[i].x * wv[j].x + hv[i].y * wv[j].y +
                       hv[i].z * wv[j].z + hv[i].w * wv[j].w;
    }
  }
#pragma unroll
  for (int i = 0; i < 4; i++) {
    int b = bt * 64 + tb * 4 + i;
#pragma unroll
    for (int j = 0; j < 4; j++) {
      int cidx = ct * 64 + tn + 16 * j;
      Hpart[((size_t)ks * NB + b) * NC + cidx] = acc[i][j];
    }
  }
}

// ---------------------------------------------------------------------------
// Kernel 4: 16-pixel autoregressive block (register version,
// 8-partial Hpart sum).
// ---------------------------------------------------------------------------
__global__ __launch_bounds__(64) void pixel_kernel(
    const float* __restrict__ WD, const float* __restrict__ A0v,
    const float* __restrict__ Hpart, const float* __restrict__ w2,
    const float* __restrict__ b2, float* __restrict__ u_cur,
    int* __restrict__ v_cur, float* __restrict__ out_soft,
    float* __restrict__ out_u, float* __restrict__ out_v,
    int si, int sj, int t_base) {
  int b = blockIdx.x, lane = threadIdx.x;
  __shared__ float gum[32];

  int widx = (lane < 49) ? lane : 48;
  int vv = v_cur[b * 256 + (si + 1 + widx / 7) * 16 + (sj + 1 + widx % 7)];
  unsigned long long mask = __ballot((lane < 49) && (vv != 0));

  if (lane < 32) {
    int t = t_base + (lane >> 1);
    uint32_t sk0 = SUBKEYS.v[2 * t], sk1 = SUBKEYS.v[2 * t + 1];
    uint32_t bits;
#if PARTITIONABLE
    TFOut o = tf2x32(sk0, sk1, 0u, (uint32_t)(2 * b + (lane & 1)));
    bits = o.a ^ o.b;
#else
    uint32_t f = (uint32_t)(2 * b + (lane & 1));
    if (f < 256u) { TFOut o = tf2x32(sk0, sk1, f, f + 256u); bits = o.a; }
    else          { TFOut o = tf2x32(sk0, sk1, f - 256u, f); bits = o.b; }
#endif
    gum[lane] = gumbel_from_bits(bits);
  }

  float wdreg[NFS][8];
#pragma unroll
  for (int n = 0; n < NFS; n++)
#pragma unroll
    for (int r = 0; r < 8; r++) wdreg[n][r] = WD[n * NC + lane + 64 * r];

  float w2r0[8], w2r1[8];
#pragma unroll
  for (int r = 0; r < 8; r++) {
    w2r0[r] = w2[lane + 64 * r];
    w2r1[r] = w2[NC + lane + 64 * r];
  }
  double b20 = (double)b2[0], b21 = (double)b2[1];

  float base[8];
#pragma unroll
  for (int r = 0; r < 8; r++) {
    int c = lane + 64 * r;
    float v = A0v[c];
#pragma unroll
    for (int ks = 0; ks < 8; ks++) v += Hpart[((size_t)ks * NB + b) * NC + c];
    base[r] = v;
  }
  __syncthreads();

#pragma unroll 1
  for (int ii = 0; ii < 4; ii++) {
#pragma unroll 1
    for (int jj = 0; jj < 4; jj++) {
      int bofs = ii * 7 + jj;
      float acc[8];
#pragma unroll
      for (int r = 0; r < 8; r++) acc[r] = base[r];
#pragma unroll
      for (int n = 0; n < NFS; n++) {
        const int OFF = (n / 4) * 7 + (n % 4);
        float pf = (float)((unsigned)((mask >> (bofs + OFF)) & 1ull));
#pragma unroll
        for (int r = 0; r < 8; r++) acc[r] = fmaf(pf, wdreg[n][r], acc[r]);
      }
      double d0 = 0.0, d1 = 0.0;
#pragma unroll
      for (int r = 0; r < 8; r++) {
        float z = fmaxf(acc[r], 0.0f);
        d0 += (double)z * (double)w2r0[r];
        d1 += (double)z * (double)w2r1[r];
      }
#pragma unroll
      for (int off = 32; off > 0; off >>= 1) {
        d0 += __shfl_xor(d0, off, 64);
        d1 += __shfl_xor(d1, off, 64);
      }
      float r0 = (float)(d0 + b20);
      float r1 = (float)(d1 + b21);
      float m = fmaxf(r0, r1);
      float s0 = r0 - m, s1 = r1 - m;
      float lse = logf(expf(s0) + expf(s1));
      float l0 = s0 - lse, l1 = s1 - lse;
      int pidx = ii * 4 + jj;
      float a0 = l0 + gum[2 * pidx];
      float a1 = l1 + gum[2 * pidx + 1];
      int samp = (a1 > a0) ? 1 : 0;
      int tbit = bofs + 24;
      mask = (mask & ~(1ull << tbit)) | ((unsigned long long)samp << tbit);
      if (lane == 0) {
        int pr = si + ii + 4, pc = sj + jj + 4;
        size_t so = ((size_t)(b * 16 + pr) * 16 + pc) * 2;
        out_soft[so] = l0;
        out_soft[so + 1] = l1;
        int po = b * 256 + pr * 16 + pc;
        float fs = (float)samp;
        u_cur[po] = fs;
        v_cur[po] = samp;
        out_u[po] = fs;
        out_v[po] = fs;
      }
    }
  }
}

// ---------------------------------------------------------------------------
// Host-side launch sequence
// ---------------------------------------------------------------------------
extern "C" void kernel_launch(void* const* d_in, const int* in_sizes, int n_in,
                              void* d_out, int out_size, void* d_ws,
                              size_t ws_size, hipStream_t stream) {
  (void)in_sizes; (void)n_in; (void)out_size; (void)ws_size;
  const float* u_in = (const float*)d_in[0];
  const int*   v_in = (const int*)d_in[1];
  const float* emb  = (const float*)d_in[2];
  const float* w1   = (const float*)d_in[3];
  const float* b1   = (const float*)d_in[4];
  const float* w2   = (const float*)d_in[5];
  const float* b2   = (const float*)d_in[6];
  const float* wih  = (const float*)d_in[7];
  const float* whh  = (const float*)d_in[8];
  const float* bih  = (const float*)d_in[9];
  const float* bhh  = (const float*)d_in[10];

  float* ws = (float*)d_ws;
  const size_t HP = (size_t)4 * NB * NC;           // 524288: h parity stride
  float* h0buf = ws;                               // [2][4][NB][NC]
  float* cbuf  = h0buf + 2 * HP;                   // [3][NB][NC]
  float* gpart = cbuf + (size_t)3 * NB * NC;       // [2][768][2048]
  float* Hpart = gpart + (size_t)2 * 768 * 2048;   // [8][NB][NC]
  float* WDp   = Hpart + (size_t)8 * NB * NC;      // [15][NC]
  float* A0v   = WDp + NFS * NC;                   // [NC]
  float* u_cur = A0v + NC;                         // [NB][16][16]
  int*   v_cur = (int*)(u_cur + NB * NL * NL);     // [NB][16][16]

  float* out_soft = (float*)d_out;                 // [NB][16][16][2]
  float* out_u = out_soft + NB * NL * NL * 2;      // [NB][16][16]
  float* out_v = out_u + NB * NL * NL;             // [NB][16][16]

  setup_kernel<<<dim3(4096), dim3(256), 0, stream>>>(
      u_in, v_in, h0buf, cbuf, u_cur, v_cur, out_soft, out_u, out_v);
  wd_kernel<<<dim3(16), dim3(256), 0, stream>>>(emb, w1, b1, WDp, A0v);

  for (int k = 0; k < 9; k++) {
    if (k > 0) {
      int e = k - 1;
      int col0 = (e % 3 == 0) ? 4 : ((e % 3 == 1) ? 8 : 0);
      lstm_gemm_kernel<<<dim3(768), dim3(64), 0, stream>>>(
          u_cur, whh, wih, h0buf + (size_t)(e & 1) * HP, gpart, col0);
      lstm_gates_kernel<<<dim3(1536), dim3(256), 0, stream>>>(
          gpart, bih, bhh, h0buf + (size_t)((e & 1) ^ 1) * HP, cbuf);
    }
    w1h0_kernel<<<dim3(256), dim3(256), 0, stream>>>(
        h0buf + (size_t)(k & 1) * HP + (size_t)(k / 3) * NB * NC, w1, Hpart);
    pixel_kernel<<<dim3(256), dim3(64), 0, stream>>>(
        WDp, A0v, Hpart, w2, b2, u_cur, v_cur, out_soft, out_u, out_v,
        (k / 3) * 4, (k % 3) * 4, k * 16);
  }
}

// Round 7
// 873.328 us; speedup vs baseline: 3.6565x; 3.6565x over previous
//
#include <hip/hip_runtime.h>
#include <cstdint>
#include <cstddef>

// ---------------------------------------------------------------------------
// Problem constants
// ---------------------------------------------------------------------------
constexpr int NB = 256;   // batch
constexpr int NC = 512;   // c_length
constexpr int NL = 16;    // lattice side
constexpr int NFS = 15;   // neighborhood size

#define PARTITIONABLE 1

// ---------------------------------------------------------------------------
// Threefry2x32-20 (JAX-compatible), usable at compile time and on device
// ---------------------------------------------------------------------------
struct TFOut { uint32_t a, b; };

__host__ __device__ constexpr uint32_t rotl32(uint32_t x, int d) {
  return (x << d) | (x >> (32 - d));
}

__host__ __device__ constexpr TFOut tf2x32(uint32_t k0, uint32_t k1,
                                           uint32_t x0, uint32_t x1) {
  uint32_t k2 = k0 ^ k1 ^ 0x1BD11BDAu;
  x0 += k0; x1 += k1;
  const int R0[4] = {13, 15, 26, 6};
  const int R1[4] = {17, 29, 16, 24};
  for (int i = 0; i < 4; i++) { x0 += x1; x1 = rotl32(x1, R0[i]); x1 ^= x0; }
  x0 += k1; x1 += k2 + 1u;
  for (int i = 0; i < 4; i++) { x0 += x1; x1 = rotl32(x1, R1[i]); x1 ^= x0; }
  x0 += k2; x1 += k0 + 2u;
  for (int i = 0; i < 4; i++) { x0 += x1; x1 = rotl32(x1, R0[i]); x1 ^= x0; }
  x0 += k0; x1 += k1 + 3u;
  for (int i = 0; i < 4; i++) { x0 += x1; x1 = rotl32(x1, R1[i]); x1 ^= x0; }
  x0 += k1; x1 += k2 + 4u;
  for (int i = 0; i < 4; i++) { x0 += x1; x1 = rotl32(x1, R0[i]); x1 ^= x0; }
  x0 += k2; x1 += k0 + 5u;
  return TFOut{x0, x1};
}

struct SubKeys { uint32_t v[288]; };

constexpr SubKeys make_subkeys() {
  SubKeys s{};
  uint32_t k0 = 0u, k1 = 1234u;
  for (int t = 0; t < 144; t++) {
#if PARTITIONABLE
    TFOut nk = tf2x32(k0, k1, 0u, 0u);
    TFOut sk = tf2x32(k0, k1, 0u, 1u);
    s.v[2 * t] = sk.a; s.v[2 * t + 1] = sk.b;
    k0 = nk.a; k1 = nk.b;
#else
    TFOut p0 = tf2x32(k0, k1, 0u, 2u);
    TFOut p1 = tf2x32(k0, k1, 1u, 3u);
    s.v[2 * t] = p0.b; s.v[2 * t + 1] = p1.b;
    k0 = p0.a; k1 = p1.a;
#endif
  }
  return s;
}

__constant__ SubKeys SUBKEYS = make_subkeys();

__device__ __forceinline__ float gumbel_from_bits(uint32_t bits) {
  uint32_t ub = (bits >> 9) | 0x3f800000u;
  float f = __uint_as_float(ub) - 1.0f;
  float u = (f == 0.0f) ? 1.17549435e-38f : f;
  float inner = logf(u);
  float outer = logf(-inner);
  return -outer;
}

__device__ __forceinline__ float4 f4fma(float a, float4 b, float4 c) {
  return make_float4(fmaf(a, b.x, c.x), fmaf(a, b.y, c.y),
                     fmaf(a, b.z, c.z), fmaf(a, b.w, c.w));
}

// ---------------------------------------------------------------------------
// Kernel 0: init workspace + outputs
// ---------------------------------------------------------------------------
__global__ __launch_bounds__(256) void setup_kernel(
    const float* __restrict__ u_in, const int* __restrict__ v_in,
    float* __restrict__ h0buf, float* __restrict__ cbuf,
    float* __restrict__ u_cur, int* __restrict__ v_cur,
    float* __restrict__ out_soft, float* __restrict__ out_u,
    float* __restrict__ out_v) {
  int idx = blockIdx.x * 256 + threadIdx.x;
  h0buf[idx] = 0.0f;                         // 2 parities x [4][NB][NC]
  if (idx < 3 * NB * NC) cbuf[idx] = 0.0f;   // lstm cell state, 3 sectors
  if (idx < NB * NL * NL) {
    float uv = u_in[idx];
    int vv = v_in[idx];
    u_cur[idx] = uv;
    v_cur[idx] = vv;
    out_u[idx] = uv;
    out_v[idx] = (float)vv;
  }
  if (idx < NB * NL * NL * 2) out_soft[idx] = 0.0f;
}

// ---------------------------------------------------------------------------
// Transpose: in[R][C] -> out[C][R], R,C multiples of 64 (16 iters = full tile)
// ---------------------------------------------------------------------------
__global__ __launch_bounds__(256) void transpose_kernel(
    const float* __restrict__ in, float* __restrict__ out, int R, int C) {
  __shared__ float tile[64][65];
  int tc = blockIdx.x % (C >> 6);
  int tr = blockIdx.x / (C >> 6);
  int tid = threadIdx.x;
  for (int it = 0; it < 16; it++) {
    int idx = it * 256 + tid;
    int rr = idx >> 6, cc = idx & 63;
    tile[rr][cc] = in[(size_t)(tr * 64 + rr) * C + tc * 64 + cc];
  }
  __syncthreads();
  for (int it = 0; it < 16; it++) {
    int idx = it * 256 + tid;
    int rr = idx >> 6, cc = idx & 63;
    out[(size_t)(tc * 64 + rr) * R + tr * 64 + cc] = tile[cc][rr];
  }
}

// wih[2048][16] -> wihT[16][2048]
__global__ __launch_bounds__(256) void wih_t_kernel(
    const float* __restrict__ wih, float* __restrict__ wihT) {
  int idx = blockIdx.x * 256 + threadIdx.x;   // 32768
  int n = idx >> 11, cg = idx & 2047;
  wihT[(size_t)n * 2048 + cg] = wih[cg * 16 + n];
}

// ---------------------------------------------------------------------------
// Kernel 1: WD[n][c] = W1 · (emb[n,1]-emb[n,0]);  A0 = W1 · Σ emb[n,0] + b1
// ---------------------------------------------------------------------------
__global__ __launch_bounds__(256) void wd_kernel(
    const float* __restrict__ emb, const float* __restrict__ w1,
    const float* __restrict__ b1, float* __restrict__ WD,
    float* __restrict__ A0v) {
  __shared__ double dvec[NC];
  int n = blockIdx.x, tid = threadIdx.x;
  for (int k = tid; k < NC; k += 256) {
    if (n < NFS) {
      dvec[k] = (double)emb[(n * 2 + 1) * NC + k] - (double)emb[(n * 2) * NC + k];
    } else {
      double s = 0.0;
      for (int nn = 0; nn < NFS; nn++) s += (double)emb[(nn * 2) * NC + k];
      dvec[k] = s;
    }
  }
  __syncthreads();
  for (int c = tid; c < NC; c += 256) {
    double acc = 0.0;
    const float* wrow = w1 + (size_t)c * NC;
    for (int k = 0; k < NC; k++) acc += dvec[k] * (double)wrow[k];
    if (n < NFS) WD[n * NC + c] = (float)acc;
    else         A0v[c] = (float)(acc + (double)b1[c]);
  }
}

// ---------------------------------------------------------------------------
// Kernel 2a: LSTM GEMM — h in LDS (broadcast reads), whhT from global
// (k-major, coalesced, L1/L3-cached). Per-thread 4 rows x 4 consecutive cols.
// Block 256 thr = 64 rows x 64 cols; grid = 2(kz) * 12(rt) * 32(ct) = 768
// -> 3 blocks/CU, 12 waves/CU. acc = 16 VGPRs: no spill.
// kz=0: k in [0,256); kz=1: [256,512). Biases + uv moved to gates kernel.
// ---------------------------------------------------------------------------
__global__ __launch_bounds__(256) void lstm_gemm_kernel(
    const float* __restrict__ whhT, const float* __restrict__ h_in,
    float* __restrict__ gpart) {
  int bx = blockIdx.x;
  int kz = bx & 1;
  int t = bx >> 1;                 // [0,384)
  int ct = t & 31;
  int rt = t >> 5;                 // [0,12)
  int row0 = rt * 64;
  int colbase = ct * 64;
  int tid = threadIdx.x, tn = tid & 15, tb = tid >> 4;

  __shared__ float hs[64 * 36];
  const float* hbase = h_in + (size_t)row0 * NC;
  const float* wbase = whhT + colbase + tn * 4;

  float4 acc[4];
#pragma unroll
  for (int i = 0; i < 4; i++) acc[i] = make_float4(0.f, 0.f, 0.f, 0.f);

  int kbase = kz * 256;
  for (int kc = 0; kc < 8; kc++) {
    int k0 = kbase + kc * 32;
    __syncthreads();
#pragma unroll
    for (int tq = 0; tq < 2; tq++) {
      int lin = tq * 256 + tid;          // [0,512)
      int r = lin >> 3, kk4 = lin & 7;
      *(float4*)&hs[r * 36 + kk4 * 4] =
          *(const float4*)(hbase + (size_t)r * NC + k0 + kk4 * 4);
    }
    __syncthreads();
#pragma unroll
    for (int kk4 = 0; kk4 < 8; kk4++) {
      int k = k0 + kk4 * 4;
      float4 wv0 = *(const float4*)(wbase + (size_t)k * 2048);
      float4 wv1 = *(const float4*)(wbase + (size_t)(k + 1) * 2048);
      float4 wv2 = *(const float4*)(wbase + (size_t)(k + 2) * 2048);
      float4 wv3 = *(const float4*)(wbase + (size_t)(k + 3) * 2048);
      float4 hv[4];
#pragma unroll
      for (int i = 0; i < 4; i++)
        hv[i] = *(float4*)&hs[(tb * 4 + i) * 36 + kk4 * 4];
#pragma unroll
      for (int i = 0; i < 4; i++) {
        acc[i] = f4fma(hv[i].x, wv0, acc[i]);
        acc[i] = f4fma(hv[i].y, wv1, acc[i]);
        acc[i] = f4fma(hv[i].z, wv2, acc[i]);
        acc[i] = f4fma(hv[i].w, wv3, acc[i]);
      }
    }
  }

  float* gp = gpart + (size_t)kz * 768 * 2048;
#pragma unroll
  for (int i = 0; i < 4; i++) {
    int grow = row0 + tb * 4 + i;
    *(float4*)&gp[(size_t)grow * 2048 + colbase + tn * 4] = acc[i];
  }
}

// ---------------------------------------------------------------------------
// Kernel 2b: reduce split-K partials + uv@wihT + bias + LSTM nonlinearity.
// One block = half a row (256 cols); row-uniform uv -> broadcast loads;
// wihT loads coalesced. grid = 1536 x 256.
// ---------------------------------------------------------------------------
__global__ __launch_bounds__(256) void lstm_gates_kernel(
    const float* __restrict__ gpart, const float* __restrict__ wihT,
    const float* __restrict__ u_cur, const float* __restrict__ bih,
    const float* __restrict__ bhh, float* __restrict__ h_out,
    float* __restrict__ cbuf, int col0) {
  int idx = blockIdx.x * 256 + threadIdx.x;   // [0, 393216)
  int row = idx >> 9, c = idx & 511;
  int s = row >> 8, b = row & 255;
  const float* gp0 = gpart;
  const float* gp1 = gpart + (size_t)768 * 2048;
  size_t base = (size_t)row * 2048 + c;

  float uvv[16];
#pragma unroll
  for (int n = 0; n < 16; n++)
    uvv[n] = u_cur[b * 256 + (s * 4 + (n >> 2)) * 16 + col0 + (n & 3)];

  float gv[4];
#pragma unroll
  for (int g = 0; g < 4; g++) {
    int nidx = g * 512 + c;
    gv[g] = gp0[base + g * 512] + gp1[base + g * 512] + bih[nidx] + bhh[nidx];
#pragma unroll
    for (int n = 0; n < 16; n++)
      gv[g] = fmaf(uvv[n], wihT[(size_t)n * 2048 + nidx], gv[g]);
  }

  size_t off = (size_t)row * NC + c;
  float c_old = cbuf[off];
  float sig_i = 1.0f / (1.0f + expf(-gv[0]));
  float sig_f = 1.0f / (1.0f + expf(-gv[1]));
  float tg    = tanhf(gv[2]);
  float sig_o = 1.0f / (1.0f + expf(-gv[3]));
  float cn = sig_f * c_old + sig_i * tg;
  float hn = sig_o * tanhf(cn);
  cbuf[off] = cn;
  h_out[off] = hn;
}

// ---------------------------------------------------------------------------
// Kernel 3: Hpart[kz][b][c] partials of H = W1 · h0 — same structure as the
// LSTM GEMM (h in LDS broadcast, w1T global coalesced). split-K=16 (K=32).
// grid = 16(kz) * 4(rt) * 8(ct) = 512 blocks -> 2 blocks/CU, 8 waves/CU.
// ---------------------------------------------------------------------------
__global__ __launch_bounds__(256) void w1h0_kernel(
    const float* __restrict__ w1T, const float* __restrict__ h_in,
    float* __restrict__ Hpart) {
  int bx = blockIdx.x;
  int kz = bx & 15;
  int t = bx >> 4;                 // [0,32)
  int ct = t & 7;
  int rt = t >> 3;                 // [0,4)
  int row0 = rt * 64;
  int colbase = ct * 64;
  int tid = threadIdx.x, tn = tid & 15, tb = tid >> 4;

  __shared__ float hs[64 * 36];
  const float* hbase = h_in + (size_t)row0 * NC;
  const float* wbase = w1T + colbase + tn * 4;
  int k0 = kz * 32;

#pragma unroll
  for (int tq = 0; tq < 2; tq++) {
    int lin = tq * 256 + tid;
    int r = lin >> 3, kk4 = lin & 7;
    *(float4*)&hs[r * 36 + kk4 * 4] =
        *(const float4*)(hbase + (size_t)r * NC + k0 + kk4 * 4);
  }
  __syncthreads();

  float4 acc[4];
#pragma unroll
  for (int i = 0; i < 4; i++) acc[i] = make_float4(0.f, 0.f, 0.f, 0.f);

#pragma unroll
  for (int kk4 = 0; kk4 < 8; kk4++) {
    int k = k0 + kk4 * 4;
    float4 wv0 = *(const float4*)(wbase + (size_t)k * NC);
    float4 wv1 = *(const float4*)(wbase + (size_t)(k + 1) * NC);
    float4 wv2 = *(const float4*)(wbase + (size_t)(k + 2) * NC);
    float4 wv3 = *(const float4*)(wbase + (size_t)(k + 3) * NC);
    float4 hv[4];
#pragma unroll
    for (int i = 0; i < 4; i++)
      hv[i] = *(float4*)&hs[(tb * 4 + i) * 36 + kk4 * 4];
#pragma unroll
    for (int i = 0; i < 4; i++) {
      acc[i] = f4fma(hv[i].x, wv0, acc[i]);
      acc[i] = f4fma(hv[i].y, wv1, acc[i]);
      acc[i] = f4fma(hv[i].z, wv2, acc[i]);
      acc[i] = f4fma(hv[i].w, wv3, acc[i]);
    }
  }
#pragma unroll
  for (int i = 0; i < 4; i++) {
    int b = row0 + tb * 4 + i;
    *(float4*)&Hpart[((size_t)kz * NB + b) * NC + colbase + tn * 4] = acc[i];
  }
}

// ---------------------------------------------------------------------------
// Kernel 4: 16-pixel autoregressive block (register version, 16 partials).
// ---------------------------------------------------------------------------
__global__ __launch_bounds__(64) void pixel_kernel(
    const float* __restrict__ WD, const float* __restrict__ A0v,
    const float* __restrict__ Hpart, const float* __restrict__ w2,
    const float* __restrict__ b2, float* __restrict__ u_cur,
    int* __restrict__ v_cur, float* __restrict__ out_soft,
    float* __restrict__ out_u, float* __restrict__ out_v,
    int si, int sj, int t_base) {
  int b = blockIdx.x, lane = threadIdx.x;
  __shared__ float gum[32];

  int widx = (lane < 49) ? lane : 48;
  int vv = v_cur[b * 256 + (si + 1 + widx / 7) * 16 + (sj + 1 + widx % 7)];
  unsigned long long mask = __ballot((lane < 49) && (vv != 0));

  if (lane < 32) {
    int t = t_base + (lane >> 1);
    uint32_t sk0 = SUBKEYS.v[2 * t], sk1 = SUBKEYS.v[2 * t + 1];
    uint32_t bits;
#if PARTITIONABLE
    TFOut o = tf2x32(sk0, sk1, 0u, (uint32_t)(2 * b + (lane & 1)));
    bits = o.a ^ o.b;
#else
    uint32_t f = (uint32_t)(2 * b + (lane & 1));
    if (f < 256u) { TFOut o = tf2x32(sk0, sk1, f, f + 256u); bits = o.a; }
    else          { TFOut o = tf2x32(sk0, sk1, f - 256u, f); bits = o.b; }
#endif
    gum[lane] = gumbel_from_bits(bits);
  }

  float wdreg[NFS][8];
#pragma unroll
  for (int n = 0; n < NFS; n++)
#pragma unroll
    for (int r = 0; r < 8; r++) wdreg[n][r] = WD[n * NC + lane + 64 * r];

  float w2r0[8], w2r1[8];
#pragma unroll
  for (int r = 0; r < 8; r++) {
    w2r0[r] = w2[lane + 64 * r];
    w2r1[r] = w2[NC + lane + 64 * r];
  }
  double b20 = (double)b2[0], b21 = (double)b2[1];

  float base[8];
#pragma unroll
  for (int r = 0; r < 8; r++) {
    int c = lane + 64 * r;
    float v = A0v[c];
#pragma unroll
    for (int ks = 0; ks < 16; ks++) v += Hpart[((size_t)ks * NB + b) * NC + c];
    base[r] = v;
  }
  __syncthreads();

#pragma unroll 1
  for (int ii = 0; ii < 4; ii++) {
#pragma unroll 1
    for (int jj = 0; jj < 4; jj++) {
      int bofs = ii * 7 + jj;
      float acc[8];
#pragma unroll
      for (int r = 0; r < 8; r++) acc[r] = base[r];
#pragma unroll
      for (int n = 0; n < NFS; n++) {
        const int OFF = (n / 4) * 7 + (n % 4);
        float pf = (float)((unsigned)((mask >> (bofs + OFF)) & 1ull));
#pragma unroll
        for (int r = 0; r < 8; r++) acc[r] = fmaf(pf, wdreg[n][r], acc[r]);
      }
      double d0 = 0.0, d1 = 0.0;
#pragma unroll
      for (int r = 0; r < 8; r++) {
        float z = fmaxf(acc[r], 0.0f);
        d0 += (double)z * (double)w2r0[r];
        d1 += (double)z * (double)w2r1[r];
      }
#pragma unroll
      for (int off = 32; off > 0; off >>= 1) {
        d0 += __shfl_xor(d0, off, 64);
        d1 += __shfl_xor(d1, off, 64);
      }
      float r0 = (float)(d0 + b20);
      float r1 = (float)(d1 + b21);
      float m = fmaxf(r0, r1);
      float s0 = r0 - m, s1 = r1 - m;
      float lse = logf(expf(s0) + expf(s1));
      float l0 = s0 - lse, l1 = s1 - lse;
      int pidx = ii * 4 + jj;
      float a0 = l0 + gum[2 * pidx];
      float a1 = l1 + gum[2 * pidx + 1];
      int samp = (a1 > a0) ? 1 : 0;
      int tbit = bofs + 24;
      mask = (mask & ~(1ull << tbit)) | ((unsigned long long)samp << tbit);
      if (lane == 0) {
        int pr = si + ii + 4, pc = sj + jj + 4;
        size_t so = ((size_t)(b * 16 + pr) * 16 + pc) * 2;
        out_soft[so] = l0;
        out_soft[so + 1] = l1;
        int po = b * 256 + pr * 16 + pc;
        float fs = (float)samp;
        u_cur[po] = fs;
        v_cur[po] = samp;
        out_u[po] = fs;
        out_v[po] = fs;
      }
    }
  }
}

// ---------------------------------------------------------------------------
// Host-side launch sequence
// ---------------------------------------------------------------------------
extern "C" void kernel_launch(void* const* d_in, const int* in_sizes, int n_in,
                              void* d_out, int out_size, void* d_ws,
                              size_t ws_size, hipStream_t stream) {
  (void)in_sizes; (void)n_in; (void)out_size; (void)ws_size;
  const float* u_in = (const float*)d_in[0];
  const int*   v_in = (const int*)d_in[1];
  const float* emb  = (const float*)d_in[2];
  const float* w1   = (const float*)d_in[3];
  const float* b1   = (const float*)d_in[4];
  const float* w2   = (const float*)d_in[5];
  const float* b2   = (const float*)d_in[6];
  const float* wih  = (const float*)d_in[7];
  const float* whh  = (const float*)d_in[8];
  const float* bih  = (const float*)d_in[9];
  const float* bhh  = (const float*)d_in[10];

  float* ws = (float*)d_ws;
  const size_t HP = (size_t)4 * NB * NC;           // 524288: h parity stride
  float* h0buf = ws;                               // [2][4][NB][NC]
  float* cbuf  = h0buf + 2 * HP;                   // [3][NB][NC]
  float* gpart = cbuf + (size_t)3 * NB * NC;       // [2][768][2048]
  float* Hpart = gpart;                            // [16][NB][NC] (aliases gpart;
                                                   //  phases never overlap)
  float* whhT  = gpart + (size_t)2 * 768 * 2048;   // [512][2048]
  float* w1T   = whhT + (size_t)NC * 2048;         // [512][512]
  float* wihT  = w1T + (size_t)NC * NC;            // [16][2048]
  float* WDp   = wihT + (size_t)16 * 2048;         // [15][NC]
  float* A0v   = WDp + NFS * NC;                   // [NC]
  float* u_cur = A0v + NC;                         // [NB][16][16]
  int*   v_cur = (int*)(u_cur + NB * NL * NL);     // [NB][16][16]

  float* out_soft = (float*)d_out;                 // [NB][16][16][2]
  float* out_u = out_soft + NB * NL * NL * 2;      // [NB][16][16]
  float* out_v = out_u + NB * NL * NL;             // [NB][16][16]

  setup_kernel<<<dim3(4096), dim3(256), 0, stream>>>(
      u_in, v_in, h0buf, cbuf, u_cur, v_cur, out_soft, out_u, out_v);
  wd_kernel<<<dim3(16), dim3(256), 0, stream>>>(emb, w1, b1, WDp, A0v);
  transpose_kernel<<<dim3(256), dim3(256), 0, stream>>>(whh, whhT, 2048, 512);
  transpose_kernel<<<dim3(64), dim3(256), 0, stream>>>(w1, w1T, 512, 512);
  wih_t_kernel<<<dim3(128), dim3(256), 0, stream>>>(wih, wihT);

  for (int k = 0; k < 9; k++) {
    if (k > 0) {
      int e = k - 1;
      int col0 = (e % 3 == 0) ? 4 : ((e % 3 == 1) ? 8 : 0);
      lstm_gemm_kernel<<<dim3(768), dim3(256), 0, stream>>>(
          whhT, h0buf + (size_t)(e & 1) * HP, gpart);
      lstm_gates_kernel<<<dim3(1536), dim3(256), 0, stream>>>(
          gpart, wihT, u_cur, bih, bhh,
          h0buf + (size_t)((e & 1) ^ 1) * HP, cbuf, col0);
    }
    w1h0_kernel<<<dim3(512), dim3(256), 0, stream>>>(
        w1T, h0buf + (size_t)(k & 1) * HP + (size_t)(k / 3) * NB * NC, Hpart);
    pixel_kernel<<<dim3(256), dim3(64), 0, stream>>>(
        WDp, A0v, Hpart, w2, b2, u_cur, v_cur, out_soft, out_u, out_v,
        (k / 3) * 4, (k % 3) * 4, k * 16);
  }
}

// Round 8
// 807.414 us; speedup vs baseline: 3.9550x; 1.0816x over previous
//
#include <hip/hip_runtime.h>
#include <cstdint>
#include <cstddef>

// ---------------------------------------------------------------------------
// Problem constants
// ---------------------------------------------------------------------------
constexpr int NB = 256;   // batch
constexpr int NC = 512;   // c_length
constexpr int NL = 16;    // lattice side
constexpr int NFS = 15;   // neighborhood size

#define PARTITIONABLE 1

// ---------------------------------------------------------------------------
// Threefry2x32-20 (JAX-compatible), usable at compile time and on device
// ---------------------------------------------------------------------------
struct TFOut { uint32_t a, b; };

__host__ __device__ constexpr uint32_t rotl32(uint32_t x, int d) {
  return (x << d) | (x >> (32 - d));
}

__host__ __device__ constexpr TFOut tf2x32(uint32_t k0, uint32_t k1,
                                           uint32_t x0, uint32_t x1) {
  uint32_t k2 = k0 ^ k1 ^ 0x1BD11BDAu;
  x0 += k0; x1 += k1;
  const int R0[4] = {13, 15, 26, 6};
  const int R1[4] = {17, 29, 16, 24};
  for (int i = 0; i < 4; i++) { x0 += x1; x1 = rotl32(x1, R0[i]); x1 ^= x0; }
  x0 += k1; x1 += k2 + 1u;
  for (int i = 0; i < 4; i++) { x0 += x1; x1 = rotl32(x1, R1[i]); x1 ^= x0; }
  x0 += k2; x1 += k0 + 2u;
  for (int i = 0; i < 4; i++) { x0 += x1; x1 = rotl32(x1, R0[i]); x1 ^= x0; }
  x0 += k0; x1 += k1 + 3u;
  for (int i = 0; i < 4; i++) { x0 += x1; x1 = rotl32(x1, R1[i]); x1 ^= x0; }
  x0 += k1; x1 += k2 + 4u;
  for (int i = 0; i < 4; i++) { x0 += x1; x1 = rotl32(x1, R0[i]); x1 ^= x0; }
  x0 += k2; x1 += k0 + 5u;
  return TFOut{x0, x1};
}

struct SubKeys { uint32_t v[288]; };

constexpr SubKeys make_subkeys() {
  SubKeys s{};
  uint32_t k0 = 0u, k1 = 1234u;
  for (int t = 0; t < 144; t++) {
#if PARTITIONABLE
    TFOut nk = tf2x32(k0, k1, 0u, 0u);
    TFOut sk = tf2x32(k0, k1, 0u, 1u);
    s.v[2 * t] = sk.a; s.v[2 * t + 1] = sk.b;
    k0 = nk.a; k1 = nk.b;
#else
    TFOut p0 = tf2x32(k0, k1, 0u, 2u);
    TFOut p1 = tf2x32(k0, k1, 1u, 3u);
    s.v[2 * t] = p0.b; s.v[2 * t + 1] = p1.b;
    k0 = p0.a; k1 = p1.a;
#endif
  }
  return s;
}

__constant__ SubKeys SUBKEYS = make_subkeys();

__device__ __forceinline__ float gumbel_from_bits(uint32_t bits) {
  uint32_t ub = (bits >> 9) | 0x3f800000u;
  float f = __uint_as_float(ub) - 1.0f;
  float u = (f == 0.0f) ? 1.17549435e-38f : f;
  float inner = logf(u);
  float outer = logf(-inner);
  return -outer;
}

__device__ __forceinline__ float4 f4fma(float a, float4 b, float4 c) {
  return make_float4(fmaf(a, b.x, c.x), fmaf(a, b.y, c.y),
                     fmaf(a, b.z, c.z), fmaf(a, b.w, c.w));
}

// ---------------------------------------------------------------------------
// Kernel 0: init workspace + outputs
// ---------------------------------------------------------------------------
__global__ __launch_bounds__(256) void setup_kernel(
    const float* __restrict__ u_in, const int* __restrict__ v_in,
    float* __restrict__ h0buf, float* __restrict__ cbuf,
    float* __restrict__ u_cur, int* __restrict__ v_cur,
    float* __restrict__ out_soft, float* __restrict__ out_u,
    float* __restrict__ out_v) {
  int idx = blockIdx.x * 256 + threadIdx.x;
  h0buf[idx] = 0.0f;                         // 2 parities x [4][NB][NC]
  if (idx < 3 * NB * NC) cbuf[idx] = 0.0f;   // lstm cell state, 3 sectors
  if (idx < NB * NL * NL) {
    float uv = u_in[idx];
    int vv = v_in[idx];
    u_cur[idx] = uv;
    v_cur[idx] = vv;
    out_u[idx] = uv;
    out_v[idx] = (float)vv;
  }
  if (idx < NB * NL * NL * 2) out_soft[idx] = 0.0f;
}

// ---------------------------------------------------------------------------
// Transpose: in[R][C] -> out[C][R], R,C multiples of 64 (16 iters = full tile)
// ---------------------------------------------------------------------------
__global__ __launch_bounds__(256) void transpose_kernel(
    const float* __restrict__ in, float* __restrict__ out, int R, int C) {
  __shared__ float tile[64][65];
  int tc = blockIdx.x % (C >> 6);
  int tr = blockIdx.x / (C >> 6);
  int tid = threadIdx.x;
  for (int it = 0; it < 16; it++) {
    int idx = it * 256 + tid;
    int rr = idx >> 6, cc = idx & 63;
    tile[rr][cc] = in[(size_t)(tr * 64 + rr) * C + tc * 64 + cc];
  }
  __syncthreads();
  for (int it = 0; it < 16; it++) {
    int idx = it * 256 + tid;
    int rr = idx >> 6, cc = idx & 63;
    out[(size_t)(tc * 64 + rr) * R + tr * 64 + cc] = tile[cc][rr];
  }
}

// wih[2048][16] -> wihT[16][2048]
__global__ __launch_bounds__(256) void wih_t_kernel(
    const float* __restrict__ wih, float* __restrict__ wihT) {
  int idx = blockIdx.x * 256 + threadIdx.x;   // 32768
  int n = idx >> 11, cg = idx & 2047;
  wihT[(size_t)n * 2048 + cg] = wih[cg * 16 + n];
}

// ---------------------------------------------------------------------------
// Kernel 1: WD[n][c] = W1 · (emb[n,1]-emb[n,0]);  A0 = W1 · Σ emb[n,0] + b1
// ---------------------------------------------------------------------------
__global__ __launch_bounds__(256) void wd_kernel(
    const float* __restrict__ emb, const float* __restrict__ w1,
    const float* __restrict__ b1, float* __restrict__ WD,
    float* __restrict__ A0v) {
  __shared__ double dvec[NC];
  int n = blockIdx.x, tid = threadIdx.x;
  for (int k = tid; k < NC; k += 256) {
    if (n < NFS) {
      dvec[k] = (double)emb[(n * 2 + 1) * NC + k] - (double)emb[(n * 2) * NC + k];
    } else {
      double s = 0.0;
      for (int nn = 0; nn < NFS; nn++) s += (double)emb[(nn * 2) * NC + k];
      dvec[k] = s;
    }
  }
  __syncthreads();
  for (int c = tid; c < NC; c += 256) {
    double acc = 0.0;
    const float* wrow = w1 + (size_t)c * NC;
    for (int k = 0; k < NC; k++) acc += dvec[k] * (double)wrow[k];
    if (n < NFS) WD[n * NC + c] = (float)acc;
    else         A0v[c] = (float)(acc + (double)b1[c]);
  }
}

// ---------------------------------------------------------------------------
// Kernel 2a: LSTM GEMM — h in LDS (broadcast reads), whhT from global
// (k-major, coalesced, L1/L2-cached), with SOFTWARE PREFETCH distance 1 on
// the wv panel (wA/wB double-buffer in registers) and __launch_bounds__(256,4)
// so the register allocator can keep the loads in flight (round-7 failure:
// VGPR=32 -> serial load chain, VALUBusy 21%).
// Per-thread 4 rows x 4 consecutive cols; block 64x64; grid 768 = 3 blk/CU.
// kz=0: k in [0,256); kz=1: [256,512). Biases + uv live in the gates kernel.
// ---------------------------------------------------------------------------
__global__ __launch_bounds__(256, 4) void lstm_gemm_kernel(
    const float* __restrict__ whhT, const float* __restrict__ h_in,
    float* __restrict__ gpart) {
  int bx = blockIdx.x;
  int kz = bx & 1;
  int t = bx >> 1;                 // [0,384)
  int ct = t & 31;
  int rt = t >> 5;                 // [0,12)
  int row0 = rt * 64;
  int colbase = ct * 64;
  int tid = threadIdx.x, tn = tid & 15, tb = tid >> 4;

  __shared__ float hs[64 * 36];
  const float* hbase = h_in + (size_t)row0 * NC;
  const float* wbase = whhT + colbase + tn * 4;

  float4 acc[4];
#pragma unroll
  for (int i = 0; i < 4; i++) acc[i] = make_float4(0.f, 0.f, 0.f, 0.f);

  int kbase = kz * 256;

  // initial prefetch: k = kbase .. kbase+3
  float4 wA[4], wB[4];
#pragma unroll
  for (int q = 0; q < 4; q++)
    wA[q] = *(const float4*)(wbase + (size_t)(kbase + q) * 2048);

  for (int kc = 0; kc < 8; kc++) {
    int k0 = kbase + kc * 32;
    __syncthreads();
#pragma unroll
    for (int tq = 0; tq < 2; tq++) {
      int lin = tq * 256 + tid;          // [0,512)
      int r = lin >> 3, kk4 = lin & 7;
      *(float4*)&hs[r * 36 + kk4 * 4] =
          *(const float4*)(hbase + (size_t)r * NC + k0 + kk4 * 4);
    }
    __syncthreads();
#pragma unroll
    for (int kk4 = 0; kk4 < 8; kk4++) {
      // prefetch next kk4's wv (wraps to kbase at the very end; harmless)
      int knext = (kk4 < 7) ? (k0 + kk4 * 4 + 4)
                            : ((kc < 7) ? (k0 + 32) : kbase);
#pragma unroll
      for (int q = 0; q < 4; q++)
        wB[q] = *(const float4*)(wbase + (size_t)(knext + q) * 2048);

      float4 hv[4];
#pragma unroll
      for (int i = 0; i < 4; i++)
        hv[i] = *(float4*)&hs[(tb * 4 + i) * 36 + kk4 * 4];
#pragma unroll
      for (int i = 0; i < 4; i++) {
        acc[i] = f4fma(hv[i].x, wA[0], acc[i]);
        acc[i] = f4fma(hv[i].y, wA[1], acc[i]);
        acc[i] = f4fma(hv[i].z, wA[2], acc[i]);
        acc[i] = f4fma(hv[i].w, wA[3], acc[i]);
      }
#pragma unroll
      for (int q = 0; q < 4; q++) wA[q] = wB[q];
    }
  }

  float* gp = gpart + (size_t)kz * 768 * 2048;
#pragma unroll
  for (int i = 0; i < 4; i++) {
    int grow = row0 + tb * 4 + i;
    *(float4*)&gp[(size_t)grow * 2048 + colbase + tn * 4] = acc[i];
  }
}

// ---------------------------------------------------------------------------
// Kernel 2b: reduce split-K partials + uv@wihT + bias + LSTM nonlinearity.
// One block = half a row (256 cols); row-uniform uv -> broadcast loads;
// wihT loads coalesced. grid = 1536 x 256.
// ---------------------------------------------------------------------------
__global__ __launch_bounds__(256) void lstm_gates_kernel(
    const float* __restrict__ gpart, const float* __restrict__ wihT,
    const float* __restrict__ u_cur, const float* __restrict__ bih,
    const float* __restrict__ bhh, float* __restrict__ h_out,
    float* __restrict__ cbuf, int col0) {
  int idx = blockIdx.x * 256 + threadIdx.x;   // [0, 393216)
  int row = idx >> 9, c = idx & 511;
  int s = row >> 8, b = row & 255;
  const float* gp0 = gpart;
  const float* gp1 = gpart + (size_t)768 * 2048;
  size_t base = (size_t)row * 2048 + c;

  float uvv[16];
#pragma unroll
  for (int n = 0; n < 16; n++)
    uvv[n] = u_cur[b * 256 + (s * 4 + (n >> 2)) * 16 + col0 + (n & 3)];

  float gv[4];
#pragma unroll
  for (int g = 0; g < 4; g++) {
    int nidx = g * 512 + c;
    gv[g] = gp0[base + g * 512] + gp1[base + g * 512] + bih[nidx] + bhh[nidx];
#pragma unroll
    for (int n = 0; n < 16; n++)
      gv[g] = fmaf(uvv[n], wihT[(size_t)n * 2048 + nidx], gv[g]);
  }

  size_t off = (size_t)row * NC + c;
  float c_old = cbuf[off];
  float sig_i = 1.0f / (1.0f + expf(-gv[0]));
  float sig_f = 1.0f / (1.0f + expf(-gv[1]));
  float tg    = tanhf(gv[2]);
  float sig_o = 1.0f / (1.0f + expf(-gv[3]));
  float cn = sig_f * c_old + sig_i * tg;
  float hn = sig_o * tanhf(cn);
  cbuf[off] = cn;
  h_out[off] = hn;
}

// ---------------------------------------------------------------------------
// Kernel 3: Hpart[kz][b][c] partials of H = W1 · h0 — same structure as the
// LSTM GEMM (h LDS broadcast, w1T global coalesced + register prefetch).
// split-K=16 (K=32). grid = 512 blocks -> 2 blocks/CU, 8 waves/CU.
// ---------------------------------------------------------------------------
__global__ __launch_bounds__(256, 4) void w1h0_kernel(
    const float* __restrict__ w1T, const float* __restrict__ h_in,
    float* __restrict__ Hpart) {
  int bx = blockIdx.x;
  int kz = bx & 15;
  int t = bx >> 4;                 // [0,32)
  int ct = t & 7;
  int rt = t >> 3;                 // [0,4)
  int row0 = rt * 64;
  int colbase = ct * 64;
  int tid = threadIdx.x, tn = tid & 15, tb = tid >> 4;

  __shared__ float hs[64 * 36];
  const float* hbase = h_in + (size_t)row0 * NC;
  const float* wbase = w1T + colbase + tn * 4;
  int k0 = kz * 32;

  float4 wA[4], wB[4];
#pragma unroll
  for (int q = 0; q < 4; q++)
    wA[q] = *(const float4*)(wbase + (size_t)(k0 + q) * NC);

#pragma unroll
  for (int tq = 0; tq < 2; tq++) {
    int lin = tq * 256 + tid;
    int r = lin >> 3, kk4 = lin & 7;
    *(float4*)&hs[r * 36 + kk4 * 4] =
        *(const float4*)(hbase + (size_t)r * NC + k0 + kk4 * 4);
  }
  __syncthreads();

  float4 acc[4];
#pragma unroll
  for (int i = 0; i < 4; i++) acc[i] = make_float4(0.f, 0.f, 0.f, 0.f);

#pragma unroll
  for (int kk4 = 0; kk4 < 8; kk4++) {
    int knext = (kk4 < 7) ? (k0 + kk4 * 4 + 4) : k0;
#pragma unroll
    for (int q = 0; q < 4; q++)
      wB[q] = *(const float4*)(wbase + (size_t)(knext + q) * NC);

    float4 hv[4];
#pragma unroll
    for (int i = 0; i < 4; i++)
      hv[i] = *(float4*)&hs[(tb * 4 + i) * 36 + kk4 * 4];
#pragma unroll
    for (int i = 0; i < 4; i++) {
      acc[i] = f4fma(hv[i].x, wA[0], acc[i]);
      acc[i] = f4fma(hv[i].y, wA[1], acc[i]);
      acc[i] = f4fma(hv[i].z, wA[2], acc[i]);
      acc[i] = f4fma(hv[i].w, wA[3], acc[i]);
    }
#pragma unroll
    for (int q = 0; q < 4; q++) wA[q] = wB[q];
  }
#pragma unroll
  for (int i = 0; i < 4; i++) {
    int b = row0 + tb * 4 + i;
    *(float4*)&Hpart[((size_t)kz * NB + b) * NC + colbase + tn * 4] = acc[i];
  }
}

// ---------------------------------------------------------------------------
// Kernel 4: 16-pixel autoregressive block (register version, 16 partials).
// ---------------------------------------------------------------------------
__global__ __launch_bounds__(64) void pixel_kernel(
    const float* __restrict__ WD, const float* __restrict__ A0v,
    const float* __restrict__ Hpart, const float* __restrict__ w2,
    const float* __restrict__ b2, float* __restrict__ u_cur,
    int* __restrict__ v_cur, float* __restrict__ out_soft,
    float* __restrict__ out_u, float* __restrict__ out_v,
    int si, int sj, int t_base) {
  int b = blockIdx.x, lane = threadIdx.x;
  __shared__ float gum[32];

  int widx = (lane < 49) ? lane : 48;
  int vv = v_cur[b * 256 + (si + 1 + widx / 7) * 16 + (sj + 1 + widx % 7)];
  unsigned long long mask = __ballot((lane < 49) && (vv != 0));

  if (lane < 32) {
    int t = t_base + (lane >> 1);
    uint32_t sk0 = SUBKEYS.v[2 * t], sk1 = SUBKEYS.v[2 * t + 1];
    uint32_t bits;
#if PARTITIONABLE
    TFOut o = tf2x32(sk0, sk1, 0u, (uint32_t)(2 * b + (lane & 1)));
    bits = o.a ^ o.b;
#else
    uint32_t f = (uint32_t)(2 * b + (lane & 1));
    if (f < 256u) { TFOut o = tf2x32(sk0, sk1, f, f + 256u); bits = o.a; }
    else          { TFOut o = tf2x32(sk0, sk1, f - 256u, f); bits = o.b; }
#endif
    gum[lane] = gumbel_from_bits(bits);
  }

  float wdreg[NFS][8];
#pragma unroll
  for (int n = 0; n < NFS; n++)
#pragma unroll
    for (int r = 0; r < 8; r++) wdreg[n][r] = WD[n * NC + lane + 64 * r];

  float w2r0[8], w2r1[8];
#pragma unroll
  for (int r = 0; r < 8; r++) {
    w2r0[r] = w2[lane + 64 * r];
    w2r1[r] = w2[NC + lane + 64 * r];
  }
  double b20 = (double)b2[0], b21 = (double)b2[1];

  float base[8];
#pragma unroll
  for (int r = 0; r < 8; r++) {
    int c = lane + 64 * r;
    float v = A0v[c];
#pragma unroll
    for (int ks = 0; ks < 16; ks++) v += Hpart[((size_t)ks * NB + b) * NC + c];
    base[r] = v;
  }
  __syncthreads();

#pragma unroll 1
  for (int ii = 0; ii < 4; ii++) {
#pragma unroll 1
    for (int jj = 0; jj < 4; jj++) {
      int bofs = ii * 7 + jj;
      float acc[8];
#pragma unroll
      for (int r = 0; r < 8; r++) acc[r] = base[r];
#pragma unroll
      for (int n = 0; n < NFS; n++) {
        const int OFF = (n / 4) * 7 + (n % 4);
        float pf = (float)((unsigned)((mask >> (bofs + OFF)) & 1ull));
#pragma unroll
        for (int r = 0; r < 8; r++) acc[r] = fmaf(pf, wdreg[n][r], acc[r]);
      }
      double d0 = 0.0, d1 = 0.0;
#pragma unroll
      for (int r = 0; r < 8; r++) {
        float z = fmaxf(acc[r], 0.0f);
        d0 += (double)z * (double)w2r0[r];
        d1 += (double)z * (double)w2r1[r];
      }
#pragma unroll
      for (int off = 32; off > 0; off >>= 1) {
        d0 += __shfl_xor(d0, off, 64);
        d1 += __shfl_xor(d1, off, 64);
      }
      float r0 = (float)(d0 + b20);
      float r1 = (float)(d1 + b21);
      float m = fmaxf(r0, r1);
      float s0 = r0 - m, s1 = r1 - m;
      float lse = logf(expf(s0) + expf(s1));
      float l0 = s0 - lse, l1 = s1 - lse;
      int pidx = ii * 4 + jj;
      float a0 = l0 + gum[2 * pidx];
      float a1 = l1 + gum[2 * pidx + 1];
      int samp = (a1 > a0) ? 1 : 0;
      int tbit = bofs + 24;
      mask = (mask & ~(1ull << tbit)) | ((unsigned long long)samp << tbit);
      if (lane == 0) {
        int pr = si + ii + 4, pc = sj + jj + 4;
        size_t so = ((size_t)(b * 16 + pr) * 16 + pc) * 2;
        out_soft[so] = l0;
        out_soft[so + 1] = l1;
        int po = b * 256 + pr * 16 + pc;
        float fs = (float)samp;
        u_cur[po] = fs;
        v_cur[po] = samp;
        out_u[po] = fs;
        out_v[po] = fs;
      }
    }
  }
}

// ---------------------------------------------------------------------------
// Host-side launch sequence
// ---------------------------------------------------------------------------
extern "C" void kernel_launch(void* const* d_in, const int* in_sizes, int n_in,
                              void* d_out, int out_size, void* d_ws,
                              size_t ws_size, hipStream_t stream) {
  (void)in_sizes; (void)n_in; (void)out_size; (void)ws_size;
  const float* u_in = (const float*)d_in[0];
  const int*   v_in = (const int*)d_in[1];
  const float* emb  = (const float*)d_in[2];
  const float* w1   = (const float*)d_in[3];
  const float* b1   = (const float*)d_in[4];
  const float* w2   = (const float*)d_in[5];
  const float* b2   = (const float*)d_in[6];
  const float* wih  = (const float*)d_in[7];
  const float* whh  = (const float*)d_in[8];
  const float* bih  = (const float*)d_in[9];
  const float* bhh  = (const float*)d_in[10];

  float* ws = (float*)d_ws;
  const size_t HP = (size_t)4 * NB * NC;           // 524288: h parity stride
  float* h0buf = ws;                               // [2][4][NB][NC]
  float* cbuf  = h0buf + 2 * HP;                   // [3][NB][NC]
  float* gpart = cbuf + (size_t)3 * NB * NC;       // [2][768][2048]
  float* Hpart = gpart;                            // [16][NB][NC] (aliases gpart;
                                                   //  phases never overlap)
  float* whhT  = gpart + (size_t)2 * 768 * 2048;   // [512][2048]
  float* w1T   = whhT + (size_t)NC * 2048;         // [512][512]
  float* wihT  = w1T + (size_t)NC * NC;            // [16][2048]
  float* WDp   = wihT + (size_t)16 * 2048;         // [15][NC]
  float* A0v   = WDp + NFS * NC;                   // [NC]
  float* u_cur = A0v + NC;                         // [NB][16][16]
  int*   v_cur = (int*)(u_cur + NB * NL * NL);     // [NB][16][16]

  float* out_soft = (float*)d_out;                 // [NB][16][16][2]
  float* out_u = out_soft + NB * NL * NL * 2;      // [NB][16][16]
  float* out_v = out_u + NB * NL * NL;             // [NB][16][16]

  setup_kernel<<<dim3(4096), dim3(256), 0, stream>>>(
      u_in, v_in, h0buf, cbuf, u_cur, v_cur, out_soft, out_u, out_v);
  wd_kernel<<<dim3(16), dim3(256), 0, stream>>>(emb, w1, b1, WDp, A0v);
  transpose_kernel<<<dim3(256), dim3(256), 0, stream>>>(whh, whhT, 2048, 512);
  transpose_kernel<<<dim3(64), dim3(256), 0, stream>>>(w1, w1T, 512, 512);
  wih_t_kernel<<<dim3(128), dim3(256), 0, stream>>>(wih, wihT);

  for (int k = 0; k < 9; k++) {
    if (k > 0) {
      int e = k - 1;
      int col0 = (e % 3 == 0) ? 4 : ((e % 3 == 1) ? 8 : 0);
      lstm_gemm_kernel<<<dim3(768), dim3(256), 0, stream>>>(
          whhT, h0buf + (size_t)(e & 1) * HP, gpart);
      lstm_gates_kernel<<<dim3(1536), dim3(256), 0, stream>>>(
          gpart, wihT, u_cur, bih, bhh,
          h0buf + (size_t)((e & 1) ^ 1) * HP, cbuf, col0);
    }
    w1h0_kernel<<<dim3(512), dim3(256), 0, stream>>>(
        w1T, h0buf + (size_t)(k & 1) * HP + (size_t)(k / 3) * NB * NC, Hpart);
    pixel_kernel<<<dim3(256), dim3(64), 0, stream>>>(
        WDp, A0v, Hpart, w2, b2, u_cur, v_cur, out_soft, out_u, out_v,
        (k / 3) * 4, (k % 3) * 4, k * 16);
  }
}